// Round 1
// baseline (158.813 us; speedup 1.0000x reference)
//
#include <hip/hip_runtime.h>

// Problem constants (from reference)
#define VOCAB 50000
#define SEQ   2048
#define BATCH 64
#define DIM   256
#define NC    16              // chunks over SEQ for pooling
#define CHUNK (SEQ / NC)      // 128
#define H1    100
#define H2    150

// ---------------------------------------------------------------------------
// Kernel 1: per-row tf counts + tf*idf scores.
// tokens[b][s] = x[s*BATCH + b]  (x is [SEQ, BATCH], tokens = x.T)
// tf[b][s] = #occurrences of tokens[b][s] in row b (O(S^2) LDS-broadcast scan)
// scores[b][s] = tok==0 ? 0 : tf * idf[tok]
// Grid: (4, BATCH) blocks x 512 threads; each block serves 512 positions of row b.
// ---------------------------------------------------------------------------
__global__ void k_scores(const int* __restrict__ x,
                         const float* __restrict__ idf,
                         float* __restrict__ scores) {
    __shared__ int tok[SEQ];
    const int b = blockIdx.y;
    const int part = blockIdx.x;         // 0..3
    const int t = threadIdx.x;           // 0..511

    // cooperative load of the whole row into LDS
    for (int s = t; s < SEQ; s += 512)
        tok[s] = x[s * BATCH + b];
    __syncthreads();

    const int p = part * 512 + t;        // my position
    const int mytok = tok[p];
    int cnt = 0;
    // All lanes read the same LDS address each iteration -> broadcast (free).
#pragma unroll 8
    for (int i = 0; i < SEQ; ++i)
        cnt += (tok[i] == mytok) ? 1 : 0;

    float sc = (mytok == 0) ? 0.0f : (float)cnt * idf[mytok];
    scores[b * SEQ + p] = sc;
}

// ---------------------------------------------------------------------------
// Kernel 2: pooled partials.  partials[c][b][d] = sum_{s in chunk c} emb[tok][d]*score
// Grid: (NC, BATCH) x DIM threads. Coalesced 1KB emb-row reads (4B/lane x 256).
// ---------------------------------------------------------------------------
__global__ void k_pool(const int* __restrict__ x,
                       const float* __restrict__ emb,
                       const float* __restrict__ scores,
                       float* __restrict__ partials) {
    __shared__ int   tok[CHUNK];
    __shared__ float sc[CHUNK];
    const int c = blockIdx.x;
    const int b = blockIdx.y;
    const int d = threadIdx.x;           // 0..255
    const int s0 = c * CHUNK;

    if (d < CHUNK) {
        tok[d] = x[(s0 + d) * BATCH + b];
        sc[d]  = scores[b * SEQ + s0 + d];
    }
    __syncthreads();

    float acc = 0.0f;
#pragma unroll 4
    for (int i = 0; i < CHUNK; ++i) {
        // emb row 0 is all-zero and pad score is 0, so no need to branch on pad
        const float* row = emb + (size_t)tok[i] * DIM;
        acc = fmaf(row[d], sc[i], acc);
    }
    partials[((size_t)c * BATCH + b) * DIM + d] = acc;
}

// ---------------------------------------------------------------------------
// Kernel 3: reduce partials -> pooled, then MLP (relu, relu, softmax).
// One block per batch row, 256 threads.
// ---------------------------------------------------------------------------
__global__ void k_mlp(const float* __restrict__ partials,
                      const float* __restrict__ W1, const float* __restrict__ b1,
                      const float* __restrict__ W2, const float* __restrict__ b2,
                      const float* __restrict__ W3, const float* __restrict__ b3,
                      float* __restrict__ out) {
    __shared__ float pld[DIM];
    __shared__ float h1[H1];
    __shared__ float h2[H2];
    __shared__ float logit[2];
    const int b = blockIdx.x;
    const int t = threadIdx.x;

    float acc = 0.0f;
#pragma unroll
    for (int c = 0; c < NC; ++c)
        acc += partials[((size_t)c * BATCH + b) * DIM + t];
    pld[t] = acc;
    __syncthreads();

    if (t < H1) {
        float a = b1[t];
        const float* w = W1 + t * DIM;
#pragma unroll 4
        for (int k = 0; k < DIM; ++k) a = fmaf(pld[k], w[k], a);
        h1[t] = fmaxf(a, 0.0f);
    }
    __syncthreads();

    if (t < H2) {
        float a = b2[t];
        const float* w = W2 + t * H1;
#pragma unroll 4
        for (int k = 0; k < H1; ++k) a = fmaf(h1[k], w[k], a);
        h2[t] = fmaxf(a, 0.0f);
    }
    __syncthreads();

    if (t < 2) {
        float a = b3[t];
        const float* w = W3 + t * H2;
#pragma unroll 4
        for (int k = 0; k < H2; ++k) a = fmaf(h2[k], w[k], a);
        logit[t] = a;
    }
    __syncthreads();

    if (t == 0) {
        float m  = fmaxf(logit[0], logit[1]);
        float e0 = expf(logit[0] - m);
        float e1 = expf(logit[1] - m);
        float inv = 1.0f / (e0 + e1);
        out[b * 2 + 0] = e0 * inv;
        out[b * 2 + 1] = e1 * inv;
    }
}

// ---------------------------------------------------------------------------
extern "C" void kernel_launch(void* const* d_in, const int* in_sizes, int n_in,
                              void* d_out, int out_size, void* d_ws, size_t ws_size,
                              hipStream_t stream) {
    const int*   x   = (const int*)  d_in[0];   // [SEQ, BATCH] int32
    const float* emb = (const float*)d_in[1];   // [VOCAB, DIM]
    const float* idf = (const float*)d_in[2];   // [VOCAB]
    const float* W1  = (const float*)d_in[3];   // [H1, DIM]
    const float* b1  = (const float*)d_in[4];   // [H1]
    const float* W2  = (const float*)d_in[5];   // [H2, H1]
    const float* b2  = (const float*)d_in[6];   // [H2]
    const float* W3  = (const float*)d_in[7];   // [2, H2]
    const float* b3  = (const float*)d_in[8];   // [2]
    float* out = (float*)d_out;                 // [BATCH, 2]

    // workspace layout
    float* scores   = (float*)d_ws;                         // BATCH*SEQ   = 512 KB
    float* partials = scores + (size_t)BATCH * SEQ;         // NC*BATCH*DIM = 1 MB

    k_scores<<<dim3(4, BATCH), 512, 0, stream>>>(x, idf, scores);
    k_pool  <<<dim3(NC, BATCH), DIM, 0, stream>>>(x, emb, scores, partials);
    k_mlp   <<<BATCH, DIM, 0, stream>>>(partials, W1, b1, W2, b2, W3, b3, out);
}

// Round 2
// 158.369 us; speedup vs baseline: 1.0028x; 1.0028x over previous
//
#include <hip/hip_runtime.h>

// Problem constants (from reference)
#define VOCAB 50000
#define SEQ   2048
#define BATCH 64
#define DIM   256
#define NC    16              // chunks over SEQ for pooling
#define CHUNK (SEQ / NC)      // 128
#define H1    100
#define H2    150
#define HASH  4096            // per-row hash table (load factor <= 0.5)

// ---------------------------------------------------------------------------
// Kernel 1: per-row tf counts + tf*idf scores via LDS hash histogram.
// One block per batch row. Insert 2048 tokens (atomicCAS open addressing),
// then look up counts. ~100x less work than the O(S^2) scan.
// ---------------------------------------------------------------------------
__global__ __launch_bounds__(1024)
void k_scores(const int* __restrict__ x,
              const float* __restrict__ idf,
              float* __restrict__ scores) {
    __shared__ int   tok[SEQ];
    __shared__ int   hkey[HASH];
    __shared__ int   hcnt[HASH];
    const int b = blockIdx.x;
    const int t = threadIdx.x;            // 0..1023

    for (int i = t; i < HASH; i += 1024) { hkey[i] = -1; hcnt[i] = 0; }
    for (int s = t; s < SEQ; s += 1024)  tok[s] = x[s * BATCH + b];
    __syncthreads();

    // insert phase
    for (int s = t; s < SEQ; s += 1024) {
        const int mytok = tok[s];
        unsigned h = ((unsigned)mytok * 2654435761u) >> 20;   // top 12 bits
        while (true) {
            int prev = atomicCAS(&hkey[h], -1, mytok);
            if (prev == -1 || prev == mytok) { atomicAdd(&hcnt[h], 1); break; }
            h = (h + 1) & (HASH - 1);
        }
    }
    __syncthreads();

    // lookup phase
    for (int s = t; s < SEQ; s += 1024) {
        const int mytok = tok[s];
        unsigned h = ((unsigned)mytok * 2654435761u) >> 20;
        while (hkey[h] != mytok) h = (h + 1) & (HASH - 1);
        float sc = (mytok == 0) ? 0.0f : (float)hcnt[h] * idf[mytok];
        scores[b * SEQ + s] = sc;
    }
}

// ---------------------------------------------------------------------------
// Kernel 2: pooled partials, float4 gather.
// Block = 256 threads = 4 waves. Each wave covers all 256 dims (64 lanes x
// float4) and a quarter of the chunk's s-positions; cross-wave reduce in LDS.
// ---------------------------------------------------------------------------
__global__ __launch_bounds__(256)
void k_pool(const int* __restrict__ x,
            const float* __restrict__ emb,
            const float* __restrict__ scores,
            float* __restrict__ partials) {
    __shared__ int   tok[CHUNK];
    __shared__ float sc[CHUNK];
    __shared__ float acc_lds[4][DIM];
    const int c = blockIdx.x;
    const int b = blockIdx.y;
    const int t = threadIdx.x;            // 0..255
    const int wave = t >> 6, lane = t & 63;
    const int s0 = c * CHUNK;

    if (t < CHUNK) {
        tok[t] = x[(s0 + t) * BATCH + b];
        sc[t]  = scores[b * SEQ + s0 + t];
    }
    __syncthreads();

    float4 acc = make_float4(0.f, 0.f, 0.f, 0.f);
    for (int i = wave; i < CHUNK; i += 4) {
        const float s = sc[i];
        const float4 v = ((const float4*)(emb + (size_t)tok[i] * DIM))[lane];
        acc.x = fmaf(v.x, s, acc.x);
        acc.y = fmaf(v.y, s, acc.y);
        acc.z = fmaf(v.z, s, acc.z);
        acc.w = fmaf(v.w, s, acc.w);
    }
    ((float4*)acc_lds[wave])[lane] = acc;
    __syncthreads();

    if (t < DIM) {
        float r = acc_lds[0][t] + acc_lds[1][t] + acc_lds[2][t] + acc_lds[3][t];
        partials[((size_t)c * BATCH + b) * DIM + t] = r;
    }
}

// ---------------------------------------------------------------------------
// Kernel 3: reduce partials -> pooled, MLP with wave shuffle-reductions.
// One block per batch row, 256 threads = 4 waves.
// ---------------------------------------------------------------------------
__global__ __launch_bounds__(256)
void k_mlp(const float* __restrict__ partials,
           const float* __restrict__ W1, const float* __restrict__ b1,
           const float* __restrict__ W2, const float* __restrict__ b2,
           const float* __restrict__ W3, const float* __restrict__ b3,
           float* __restrict__ out) {
    __shared__ float pld[DIM];
    __shared__ float h1[112];     // 100 used, padded
    __shared__ float h2[152];     // 150 used
    __shared__ float logit[2];
    const int b = blockIdx.x;
    const int t = threadIdx.x;    // 0..255
    const int wave = t >> 6, lane = t & 63;

    float a = 0.0f;
#pragma unroll
    for (int c = 0; c < NC; ++c)
        a += partials[((size_t)c * BATCH + b) * DIM + t];
    pld[t] = a;
    __syncthreads();

    // stage 1: h1[j] = relu(W1[j,:] . pld + b1[j]);  coalesced float4 rows
    for (int j = wave; j < H1; j += 4) {
        const float4 wv = ((const float4*)(W1 + j * DIM))[lane];
        const float4 pv = ((const float4*)pld)[lane];
        float d = wv.x * pv.x + wv.y * pv.y + wv.z * pv.z + wv.w * pv.w;
#pragma unroll
        for (int off = 32; off; off >>= 1) d += __shfl_down(d, off);
        if (lane == 0) h1[j] = fmaxf(d + b1[j], 0.0f);
    }
    __syncthreads();

    // stage 2: h2[j] = relu(W2[j,:] . h1 + b2[j]);  100 floats = 25 float4
    for (int j = wave; j < H2; j += 4) {
        float d = 0.0f;
        if (lane < 25) {
            const float4 wv = ((const float4*)(W2 + j * H1))[lane];
            const float4 hv = ((const float4*)h1)[lane];
            d = wv.x * hv.x + wv.y * hv.y + wv.z * hv.z + wv.w * hv.w;
        }
#pragma unroll
        for (int off = 32; off; off >>= 1) d += __shfl_down(d, off);
        if (lane == 0) h2[j] = fmaxf(d + b2[j], 0.0f);
    }
    __syncthreads();

    // stage 3: 2 logits over 150 elems; waves 0,1
    if (wave < 2) {
        const int j = wave;
        float d = 0.0f;
        for (int k = lane; k < H2; k += 64) d += W3[j * H2 + k] * h2[k];
#pragma unroll
        for (int off = 32; off; off >>= 1) d += __shfl_down(d, off);
        if (lane == 0) logit[j] = d + b3[j];
    }
    __syncthreads();

    if (t == 0) {
        const float m  = fmaxf(logit[0], logit[1]);
        const float e0 = __expf(logit[0] - m);
        const float e1 = __expf(logit[1] - m);
        const float inv = 1.0f / (e0 + e1);
        out[b * 2 + 0] = e0 * inv;
        out[b * 2 + 1] = e1 * inv;
    }
}

// ---------------------------------------------------------------------------
extern "C" void kernel_launch(void* const* d_in, const int* in_sizes, int n_in,
                              void* d_out, int out_size, void* d_ws, size_t ws_size,
                              hipStream_t stream) {
    const int*   x   = (const int*)  d_in[0];   // [SEQ, BATCH] int32
    const float* emb = (const float*)d_in[1];   // [VOCAB, DIM]
    const float* idf = (const float*)d_in[2];   // [VOCAB]
    const float* W1  = (const float*)d_in[3];   // [H1, DIM]
    const float* b1  = (const float*)d_in[4];   // [H1]
    const float* W2  = (const float*)d_in[5];   // [H2, H1]
    const float* b2  = (const float*)d_in[6];   // [H2]
    const float* W3  = (const float*)d_in[7];   // [2, H2]
    const float* b3  = (const float*)d_in[8];   // [2]
    float* out = (float*)d_out;                 // [BATCH, 2]

    // workspace layout
    float* scores   = (float*)d_ws;                         // BATCH*SEQ   = 512 KB
    float* partials = scores + (size_t)BATCH * SEQ;         // NC*BATCH*DIM = 1 MB

    k_scores<<<BATCH, 1024, 0, stream>>>(x, idf, scores);
    k_pool  <<<dim3(NC, BATCH), 256, 0, stream>>>(x, emb, scores, partials);
    k_mlp   <<<BATCH, 256, 0, stream>>>(partials, W1, b1, W2, b2, W3, b3, out);
}